// Round 1
// baseline (1258.838 us; speedup 1.0000x reference)
//
#include <hip/hip_runtime.h>
#include <hip/hip_bf16.h>

// ---------------------------------------------------------------------------
// SharedSpecialistMoEFFN on MI355X (gfx950)
//
// Strategy:
//   * router (fp32) -> top-2 per token -> per-expert gathered row lists
//   * all GEMMs in fp16 MFMA (16x16x32_f16), fp32 accumulate.
//     fp16 chosen over bf16: threshold 6.8e-2 vs predicted bf16 error ~0.05;
//     fp16 error ~8x smaller, same MFMA rate (2.5 PF class).
//   * weights transposed to [N][K] fp16 during the per-launch convert pass so
//     both A and B fragments are contiguous ds_read_b128 (m97 structure).
//   * shared FFN2 plain-stores d_out; expert FFN2 atomicAdd-scatters residual.
// Workspace: ~302 MB.
// ---------------------------------------------------------------------------

#define D_MODEL 1024
#define D_FF    4096
#define N_EXP   8
#define T_TOK   8192

typedef _Float16 half8  __attribute__((ext_vector_type(8)));
typedef _Float16 half4v __attribute__((ext_vector_type(4)));
typedef float    floatx4 __attribute__((ext_vector_type(4)));

__device__ __forceinline__ float gelu_exact(float x) {
  return 0.5f * x * (1.0f + erff(x * 0.70710678118654752f));
}

__device__ __forceinline__ void gld_lds16(const _Float16* g, _Float16* l) {
  __builtin_amdgcn_global_load_lds(
      (const __attribute__((address_space(1))) void*)g,
      (__attribute__((address_space(3))) void*)l, 16, 0, 0);
}

// ---------------------------------------------------------------- converts
__global__ void convert_f32_f16(const float* __restrict__ src,
                                _Float16* __restrict__ dst, int n4) {
  int i = blockIdx.x * blockDim.x + threadIdx.x;
  if (i >= n4) return;
  float4 v = ((const float4*)src)[i];
  half4v h;
  h[0] = (_Float16)v.x; h[1] = (_Float16)v.y;
  h[2] = (_Float16)v.z; h[3] = (_Float16)v.w;
  ((half4v*)dst)[i] = h;
}

// src fp32 [R][C] row-major -> dst fp16 [C][R]  (B^T layout for GEMM)
__global__ void transpose_convert(const float* __restrict__ src,
                                  _Float16* __restrict__ dst, int R, int C) {
  const size_t msz = (size_t)R * C;
  src += msz * blockIdx.z;
  dst += msz * blockIdx.z;
  __shared__ float tile[32][33];
  int c0 = blockIdx.x * 32, r0 = blockIdx.y * 32;
  int tx = threadIdx.x, ty = threadIdx.y;   // block (32, 8)
#pragma unroll
  for (int i = 0; i < 4; ++i)
    tile[ty + i * 8][tx] = src[(size_t)(r0 + ty + i * 8) * C + c0 + tx];
  __syncthreads();
#pragma unroll
  for (int i = 0; i < 4; ++i)
    dst[(size_t)(c0 + ty + i * 8) * R + r0 + tx] = (_Float16)tile[tx][ty + i * 8];
}

// ---------------------------------------------------------------- router
// one wave per token: coalesced x reads, shuffle reduce, top-2 on lane 0
__global__ void router_kernel(const float* __restrict__ x,
                              const float* __restrict__ rw,
                              const float* __restrict__ rb,
                              int* __restrict__ sel_idx,
                              float* __restrict__ sel_w,
                              int* __restrict__ counts) {
  int lane = threadIdx.x & 63;
  int t = blockIdx.x * 4 + (threadIdx.x >> 6);
  const float* xr = x + (size_t)t * D_MODEL;
  float acc[N_EXP];
#pragma unroll
  for (int e = 0; e < N_EXP; ++e) acc[e] = 0.f;
  for (int k = lane; k < D_MODEL; k += 64) {
    float xv = xr[k];
    const float* w = rw + (size_t)k * N_EXP;
#pragma unroll
    for (int e = 0; e < N_EXP; ++e) acc[e] += xv * w[e];
  }
#pragma unroll
  for (int off = 32; off > 0; off >>= 1) {
#pragma unroll
    for (int e = 0; e < N_EXP; ++e)
      acc[e] += __shfl_down(acc[e], off, 64);
  }
  if (lane == 0) {
    float mx = -1e30f;
#pragma unroll
    for (int e = 0; e < N_EXP; ++e) { acc[e] += rb[e]; mx = fmaxf(mx, acc[e]); }
    float p[N_EXP], s = 0.f;
#pragma unroll
    for (int e = 0; e < N_EXP; ++e) { p[e] = expf(acc[e] - mx); s += p[e]; }
    float inv = 1.f / s;
#pragma unroll
    for (int e = 0; e < N_EXP; ++e) p[e] *= inv;
    // top-2, first-occurrence wins on ties (matches lax.top_k)
    int i0 = 0; float p0 = p[0];
#pragma unroll
    for (int e = 1; e < N_EXP; ++e) if (p[e] > p0) { p0 = p[e]; i0 = e; }
    int i1 = -1; float p1 = -1.f;
#pragma unroll
    for (int e = 0; e < N_EXP; ++e)
      if (e != i0 && p[e] > p1) { p1 = p[e]; i1 = e; }
    float s2 = p0 + p1 + 1e-9f;
    sel_idx[2 * t] = i0; sel_idx[2 * t + 1] = i1;
    sel_w[2 * t] = p0 / s2; sel_w[2 * t + 1] = p1 / s2;
    atomicAdd(&counts[i0 * 32], 1);   // counters padded to 128B apart
    atomicAdd(&counts[i1 * 32], 1);
  }
}

__global__ void scan_kernel(const int* __restrict__ counts,
                            int* __restrict__ offsets,
                            int* __restrict__ cursor) {
  if (threadIdx.x == 0) {
    int s = 0;
    for (int e = 0; e < N_EXP; ++e) {
      offsets[e] = s; cursor[e * 32] = s; s += counts[e * 32];
    }
    offsets[N_EXP] = s;
  }
}

__global__ void assign_kernel(const int* __restrict__ sel_idx,
                              const float* __restrict__ sel_w,
                              int* __restrict__ cursor,
                              int* __restrict__ rows,
                              float* __restrict__ rowW) {
  int t = blockIdx.x * blockDim.x + threadIdx.x;
  if (t >= T_TOK) return;
#pragma unroll
  for (int k = 0; k < 2; ++k) {
    int e = sel_idx[2 * t + k];
    int pos = atomicAdd(&cursor[e * 32], 1);
    rows[pos] = t;
    rowW[pos] = sel_w[2 * t + k];
  }
}

// ---------------------------------------------------------------- GEMM
// MODE 0: shared FFN1  H[m]        = gelu(x[m]   @ W1 + b1)   (fp16 store)
// MODE 1: expert FFN1  H[offs+m]   = gelu(x[rows[m]] @ W1e + b1e)
// MODE 2: shared FFN2  out[m]      = H[m] @ W2 + b2           (fp32 store)
// MODE 3: expert FFN2  out[rows[m]] += w[m]*(H[offs+m] @ W2e + b2e)  (atomic)
// tile 128x128, BK=32, 256 threads (2x2 waves, each 64x64), m97 staging.
template <int MODE>
__global__ __launch_bounds__(256, 3) void gemm_kernel(
    const _Float16* __restrict__ A, const _Float16* __restrict__ Bt,
    const float* __restrict__ bias, void* __restrict__ OutP,
    const int* __restrict__ rows, const float* __restrict__ rowW,
    const int* __restrict__ counts, const int* __restrict__ offsets,
    int K, int N) {
  constexpr bool EXPERT = (MODE == 1 || MODE == 3);
  const int tid = threadIdx.x;
  const int lane = tid & 63, wid = tid >> 6;
  int e = 0, M = 0, offs = 0;
  if constexpr (EXPERT) {
    e = blockIdx.z;
    M = counts[e * 32];
    offs = offsets[e];
    if ((int)blockIdx.y * 128 >= M) return;   // uniform early-exit
  }
  const int m0 = blockIdx.y * 128, n0 = blockIdx.x * 128;
  const _Float16* Bte = Bt + (size_t)e * K * N;
  const float* be = bias + (size_t)e * N;

  __shared__ __align__(16) _Float16 As[128 * 32];  // [m][k]
  __shared__ __align__(16) _Float16 Bs[128 * 32];  // [n][k]

  // staging: wave `wid` fills A-chunks {2w,2w+1} and B-chunks {2w,2w+1};
  // chunk c = rows [16c,16c+16) of the tile; lane i -> row c*16+i/4, k (i%4)*8
  const int subrow = lane >> 2, kq = lane & 3;
  const int ca0 = 2 * wid, ca1 = 2 * wid + 1;

  int la0 = m0 + ca0 * 16 + subrow;
  int la1 = m0 + ca1 * 16 + subrow;
  size_t ga0, ga1;
  if constexpr (MODE == 1) {
    int c0i = la0 < M ? la0 : M - 1;
    int c1i = la1 < M ? la1 : M - 1;
    ga0 = (size_t)rows[offs + c0i];
    ga1 = (size_t)rows[offs + c1i];
  } else if constexpr (MODE == 3) {
    ga0 = (size_t)(offs + (la0 < M ? la0 : M - 1));
    ga1 = (size_t)(offs + (la1 < M ? la1 : M - 1));
  } else {
    ga0 = (size_t)la0; ga1 = (size_t)la1;
  }
  const _Float16* aS0 = A + ga0 * K + kq * 8;
  const _Float16* aS1 = A + ga1 * K + kq * 8;
  const _Float16* bS0 = Bte + (size_t)(n0 + ca0 * 16 + subrow) * K + kq * 8;
  const _Float16* bS1 = Bte + (size_t)(n0 + ca1 * 16 + subrow) * K + kq * 8;

  _Float16* ldsA0 = As + ca0 * 512;   // wave-uniform LDS bases
  _Float16* ldsA1 = As + ca1 * 512;
  _Float16* ldsB0 = Bs + ca0 * 512;
  _Float16* ldsB1 = Bs + ca1 * 512;

  floatx4 acc[4][4] = {};

  const int wm = wid >> 1, wn = wid & 1;
  const int lr = lane & 15, qd = lane >> 4;
  // A frag: A[m=lane&15][k=quad*8+j]; B frag: B[k=quad*8+j][n=lane&15]
  const _Float16* Ard = As + (wm * 64 + lr) * 32 + qd * 8;
  const _Float16* Brd = Bs + (wn * 64 + lr) * 32 + qd * 8;

  for (int kt = 0; kt < K; kt += 32) {
    __syncthreads();
    gld_lds16(aS0, ldsA0);
    gld_lds16(aS1, ldsA1);
    gld_lds16(bS0, ldsB0);
    gld_lds16(bS1, ldsB1);
    aS0 += 32; aS1 += 32; bS0 += 32; bS1 += 32;
    asm volatile("s_waitcnt vmcnt(0)" ::: "memory");
    __syncthreads();
    half8 af[4], bf[4];
#pragma unroll
    for (int mi = 0; mi < 4; ++mi)
      af[mi] = *(const half8*)(Ard + mi * 16 * 32);
#pragma unroll
    for (int ni = 0; ni < 4; ++ni)
      bf[ni] = *(const half8*)(Brd + ni * 16 * 32);
#pragma unroll
    for (int mi = 0; mi < 4; ++mi) {
#pragma unroll
      for (int ni = 0; ni < 4; ++ni)
        acc[mi][ni] = __builtin_amdgcn_mfma_f32_16x16x32_f16(
            af[mi], bf[ni], acc[mi][ni], 0, 0, 0);
    }
  }

  // epilogue: C/D layout col=lane&15, row=quad*4+reg
#pragma unroll
  for (int mi = 0; mi < 4; ++mi) {
#pragma unroll
    for (int ni = 0; ni < 4; ++ni) {
      floatx4 v = acc[mi][ni];
#pragma unroll
      for (int r = 0; r < 4; ++r) {
        int lrow = m0 + wm * 64 + mi * 16 + qd * 4 + r;
        int col = n0 + wn * 64 + ni * 16 + lr;
        float val = v[r] + be[col];
        if constexpr (MODE == 0) {
          ((_Float16*)OutP)[(size_t)lrow * N + col] = (_Float16)gelu_exact(val);
        } else if constexpr (MODE == 1) {
          if (lrow < M)
            ((_Float16*)OutP)[(size_t)(offs + lrow) * N + col] =
                (_Float16)gelu_exact(val);
        } else if constexpr (MODE == 2) {
          ((float*)OutP)[(size_t)lrow * N + col] = val;
        } else {
          if (lrow < M) {
            int tkn = rows[offs + lrow];
            float w = rowW[offs + lrow];
            atomicAdd(((float*)OutP) + (size_t)tkn * N + col, w * val);
          }
        }
      }
    }
  }
}

// ---------------------------------------------------------------- launch
extern "C" void kernel_launch(void* const* d_in, const int* in_sizes, int n_in,
                              void* d_out, int out_size, void* d_ws,
                              size_t ws_size, hipStream_t stream) {
  const float* x   = (const float*)d_in[0];
  const float* sw1 = (const float*)d_in[1];
  const float* sb1 = (const float*)d_in[2];
  const float* sw2 = (const float*)d_in[3];
  const float* sb2 = (const float*)d_in[4];
  const float* rw  = (const float*)d_in[5];
  const float* rb  = (const float*)d_in[6];
  const float* ew1 = (const float*)d_in[7];
  const float* eb1 = (const float*)d_in[8];
  const float* ew2 = (const float*)d_in[9];
  const float* eb2 = (const float*)d_in[10];
  float* out = (float*)d_out;

  char* ws = (char*)d_ws;
  size_t off = 0;
  auto alloc = [&](size_t bytes) {
    void* p = ws + off;
    off += (bytes + 255) & ~(size_t)255;
    return p;
  };
  _Float16* xb   = (_Float16*)alloc((size_t)T_TOK * D_MODEL * 2);
  _Float16* sw1t = (_Float16*)alloc((size_t)D_FF * D_MODEL * 2);
  _Float16* sw2t = (_Float16*)alloc((size_t)D_MODEL * D_FF * 2);
  _Float16* ew1t = (_Float16*)alloc((size_t)N_EXP * D_FF * D_MODEL * 2);
  _Float16* ew2t = (_Float16*)alloc((size_t)N_EXP * D_MODEL * D_FF * 2);
  _Float16* H    = (_Float16*)alloc((size_t)2 * T_TOK * D_FF * 2); // 16384 rows
  int*   sel_idx = (int*)alloc((size_t)T_TOK * 2 * 4);
  float* sel_w   = (float*)alloc((size_t)T_TOK * 2 * 4);
  int*   rows    = (int*)alloc((size_t)2 * T_TOK * 4);
  float* rowW    = (float*)alloc((size_t)2 * T_TOK * 4);
  int*   counts  = (int*)alloc(N_EXP * 32 * 4);
  int*   offsets = (int*)alloc(16 * 4);
  int*   cursor  = (int*)alloc(N_EXP * 32 * 4);
  (void)ws_size; (void)in_sizes; (void)n_in; (void)out_size;

  hipMemsetAsync(counts, 0, N_EXP * 32 * 4, stream);

  // fp32 -> fp16 converts (+ B^T transposes)
  convert_f32_f16<<<(T_TOK * D_MODEL / 4 + 255) / 256, 256, 0, stream>>>(
      x, xb, T_TOK * D_MODEL / 4);
  dim3 tb(32, 8);
  transpose_convert<<<dim3(D_FF / 32, D_MODEL / 32, 1), tb, 0, stream>>>(
      sw1, sw1t, D_MODEL, D_FF);
  transpose_convert<<<dim3(D_MODEL / 32, D_FF / 32, 1), tb, 0, stream>>>(
      sw2, sw2t, D_FF, D_MODEL);
  transpose_convert<<<dim3(D_FF / 32, D_MODEL / 32, N_EXP), tb, 0, stream>>>(
      ew1, ew1t, D_MODEL, D_FF);
  transpose_convert<<<dim3(D_MODEL / 32, D_FF / 32, N_EXP), tb, 0, stream>>>(
      ew2, ew2t, D_FF, D_MODEL);

  // routing
  router_kernel<<<T_TOK / 4, 256, 0, stream>>>(x, rw, rb, sel_idx, sel_w, counts);
  scan_kernel<<<1, 64, 0, stream>>>(counts, offsets, cursor);
  assign_kernel<<<T_TOK / 256, 256, 0, stream>>>(sel_idx, sel_w, cursor, rows, rowW);

  // shared FFN (writes d_out), then expert FFNs (atomic residual adds)
  gemm_kernel<0><<<dim3(D_FF / 128, T_TOK / 128), 256, 0, stream>>>(
      xb, sw1t, sb1, H, nullptr, nullptr, nullptr, nullptr, D_MODEL, D_FF);
  gemm_kernel<2><<<dim3(D_MODEL / 128, T_TOK / 128), 256, 0, stream>>>(
      H, sw2t, sb2, out, nullptr, nullptr, nullptr, nullptr, D_FF, D_MODEL);
  gemm_kernel<1><<<dim3(D_FF / 128, T_TOK / 128, N_EXP), 256, 0, stream>>>(
      xb, ew1t, eb1, H, rows, nullptr, counts, offsets, D_MODEL, D_FF);
  gemm_kernel<3><<<dim3(D_MODEL / 128, T_TOK / 128, N_EXP), 256, 0, stream>>>(
      H, ew2t, eb2, out, rows, rowW, counts, offsets, D_FF, D_MODEL);
}